// Round 6
// baseline (85.912 us; speedup 1.0000x reference)
//
#include <hip/hip_runtime.h>

// Chamfer distance: srcs, tgts [B=8, D=3, N=4096] f32 -> scalar f32
//   out = mean_{b,j} min_i |s_i - t_j|^2  +  mean_{b,i} min_j |s_i - t_j|^2
//
// Round 6: (1) no LDS in the hot loop — targets are pre-packed by cd_prep and
// read via wave-uniform s_load into SGPRs (scalar cache, separate pipe);
// (2) packed fp32: v_pk_fma_f32 evaluates 2 targets/inst, v_min3_f32 folds
// both into the running min -> 2 VALU inst per pair (was 3.5).
// Fixed harness floor: ~41.7 us d_ws re-poison + ~6 us restores/gaps.

#define CD_B 8
#define CD_N 4096
#define BLK 256
#define TCH 32                 // target chunks
#define TPB (CD_N / TCH)       // 128 targets per block
#define QQ 8                   // queries per thread
#define QPB (BLK * QQ)         // 2048 queries per block
#define QCH (CD_N / QPB)       // 2 query chunks
#define NQ (2 * CD_B * CD_N)   // 65536 total queries
#define NG (CD_N / 2)          // 2048 target-pair groups per (dir,b)
#define MINS_FLOATS (TCH * NQ) // 2M floats = 8 MB ws region for partial mins

typedef __attribute__((ext_vector_type(2))) float f32x2;

// d = a*b + c elementwise; b is the (wave-uniform) SGPR-pair operand.
__device__ __forceinline__ f32x2 pk_fma_sv(f32x2 a_v, f32x2 b_s, f32x2 c_v) {
  f32x2 d;
  asm("v_pk_fma_f32 %0, %1, %2, %3" : "=v"(d) : "v"(a_v), "s"(b_s), "v"(c_v));
  return d;
}

__device__ __forceinline__ float min3f(float m, float a, float b) {
  asm("v_min3_f32 %0, %1, %2, %0" : "+v"(m) : "v"(a), "v"(b));
  return m;
}

// Pack targets: P[(dir*B+b)*NG + g] = two float4:
//   (-2x0,-2x1,-2y0,-2y1) , (-2z0,-2z1, |t0|^2, |t1|^2)
__global__ __launch_bounds__(BLK) void cd_prep(
    const float* __restrict__ srcs, const float* __restrict__ tgts,
    float4* __restrict__ P) {
  const int g   = blockIdx.x * BLK + threadIdx.x;  // 32768 pair-groups total
  const int grp = g & (NG - 1);                    // 11 bits
  const int b   = (g >> 11) & (CD_B - 1);          // 3 bits
  const int dir = g >> 14;                         // 1 bit
  const float* tb = (dir ? srcs : tgts) + b * 3 * CD_N;
  const int j = grp * 2;
  float x0 = tb[j],            x1 = tb[j + 1];
  float y0 = tb[CD_N + j],     y1 = tb[CD_N + j + 1];
  float z0 = tb[2 * CD_N + j], z1 = tb[2 * CD_N + j + 1];
  float w0 = fmaf(x0, x0, fmaf(y0, y0, z0 * z0));
  float w1 = fmaf(x1, x1, fmaf(y1, y1, z1 * z1));
  float4* Pp = P + ((size_t)(dir * CD_B + b) * NG + grp) * 2;
  Pp[0] = make_float4(-2.f * x0, -2.f * x1, -2.f * y0, -2.f * y1);
  Pp[1] = make_float4(-2.f * z0, -2.f * z1, w0, w1);
}

// ws layout: float ws[TCH][NQ]
__global__ __launch_bounds__(BLK) void cd_partial(
    const float* __restrict__ srcs, const float* __restrict__ tgts,
    const float4* __restrict__ P, float* __restrict__ ws,
    float* __restrict__ out) {
  const int bid = blockIdx.x;               // 1024 blocks
  const int tc  = bid & (TCH - 1);          // 5 bits
  const int qc  = (bid >> 5) & (QCH - 1);   // 1 bit
  const int b   = (bid >> 6) & (CD_B - 1);  // 3 bits
  const int dir = bid >> 9;                 // 1 bit
  const int tid = threadIdx.x;

  const float* qb = (dir ? tgts : srcs) + b * 3 * CD_N;
  if (bid == 0 && tid == 0) out[0] = 0.0f;  // stream-ordered before cd_reduce

  // Loop-invariant query broadcasts (VGPR pairs).
  f32x2 qx2[QQ], qy2[QQ], qz2[QQ];
  const int q0 = qc * QPB + tid;
#pragma unroll
  for (int qq = 0; qq < QQ; ++qq) {
    int q = q0 + qq * BLK;
    float sx = qb[q], sy = qb[CD_N + q], sz = qb[2 * CD_N + q];
    qx2[qq] = (f32x2){sx, sx};
    qy2[qq] = (f32x2){sy, sy};
    qz2[qq] = (f32x2){sz, sz};
  }

  float mm[QQ];
#pragma unroll
  for (int qq = 0; qq < QQ; ++qq) mm[qq] = 3.4e38f;

  // Wave-uniform target reads -> s_load into SGPRs.
  const float4* __restrict__ Pp =
      P + ((size_t)(dir * CD_B + b) * NG + tc * (TPB / 2)) * 2;
#pragma unroll 2
  for (int g = 0; g < TPB / 2; ++g) {
    float4 ab = Pp[2 * g];      // (-2x0,-2x1,-2y0,-2y1)  [SGPRs]
    float4 cd = Pp[2 * g + 1];  // (-2z0,-2z1, w0, w1)    [SGPRs]
    f32x2 cx2 = (f32x2){ab.x, ab.y};
    f32x2 cy2 = (f32x2){ab.z, ab.w};
    f32x2 cz2 = (f32x2){cd.x, cd.y};
    f32x2 cwv = (f32x2){cd.z, cd.w};  // lives in VGPRs (3rd operand slot)
#pragma unroll
    for (int qq = 0; qq < QQ; ++qq) {
      f32x2 acc = pk_fma_sv(qz2[qq], cz2, cwv);
      acc = pk_fma_sv(qy2[qq], cy2, acc);
      acc = pk_fma_sv(qx2[qq], cx2, acc);
      mm[qq] = min3f(mm[qq], acc.x, acc.y);
    }
  }

  const int gqbase = (dir * CD_B + b) * CD_N + qc * QPB + tid;
  float* wrow = ws + (size_t)tc * NQ;
#pragma unroll
  for (int qq = 0; qq < QQ; ++qq) {
    float sx = qx2[qq].x, sy = qy2[qq].x, sz = qz2[qq].x;
    float ssq = fmaf(sx, sx, fmaf(sy, sy, sz * sz));
    wrow[gqbase + qq * BLK] = mm[qq] + ssq;  // full min-dist partial
  }
}

__global__ __launch_bounds__(BLK) void cd_reduce(
    const float* __restrict__ ws, float* __restrict__ out) {
  const int q = blockIdx.x * BLK + threadIdx.x;  // 65536 threads
  float m0 = ws[q];
  float m1 = ws[(size_t)1 * NQ + q];
#pragma unroll
  for (int tc = 2; tc < TCH; tc += 2) {
    m0 = fminf(m0, ws[(size_t)tc * NQ + q]);
    m1 = fminf(m1, ws[(size_t)(tc + 1) * NQ + q]);
  }
  float m = fminf(m0, m1);

  for (int off = 32; off; off >>= 1) m += __shfl_down(m, off, 64);
  __shared__ float wsum[BLK / 64];
  if ((threadIdx.x & 63) == 0) wsum[threadIdx.x >> 6] = m;
  __syncthreads();
  if (threadIdx.x == 0) {
    float s = (wsum[0] + wsum[1]) + (wsum[2] + wsum[3]);
    atomicAdd(out, s * (1.0f / (float)(CD_B * CD_N)));
  }
}

extern "C" void kernel_launch(void* const* d_in, const int* in_sizes, int n_in,
                              void* d_out, int out_size, void* d_ws, size_t ws_size,
                              hipStream_t stream) {
  const float* srcs = (const float*)d_in[0];
  const float* tgts = (const float*)d_in[1];
  float* out = (float*)d_out;
  float* ws_mins = (float*)d_ws;                                  // 8 MB
  float4* P = (float4*)((char*)d_ws + (size_t)MINS_FLOATS * 4);   // +1 MB

  cd_prep<<<(2 * CD_B * NG) / BLK, BLK, 0, stream>>>(srcs, tgts, P);
  cd_partial<<<2 * CD_B * QCH * TCH, BLK, 0, stream>>>(srcs, tgts, P, ws_mins, out);
  cd_reduce<<<NQ / BLK, BLK, 0, stream>>>(ws_mins, out);
}